// Round 7
// baseline (394.452 us; speedup 1.0000x reference)
//
#include <hip/hip_runtime.h>
#include <hip/hip_bf16.h>
#include <stdint.h>

#define B_ 8
#define N_ 256
#define M_ 128
#define D_ 128

typedef __attribute__((ext_vector_type(8))) short short8;
typedef __attribute__((ext_vector_type(4))) short short4v;
typedef __attribute__((ext_vector_type(4))) float f32x4;

static __device__ __forceinline__ unsigned short f2bf(float x) {
    union { float f; unsigned int u; } c; c.f = x;
    unsigned int r = (c.u + 0x7FFFu + ((c.u >> 16) & 1u)) >> 16;
    return (unsigned short)r;
}
// half-up bf16 (error <= 0.5 ulp): hot staging paths
static __device__ __forceinline__ unsigned short bfhu(float x) {
    union { float f; unsigned int u; } c; c.f = x;
    return (unsigned short)((c.u + 0x8000u) >> 16);
}
static __device__ __forceinline__ float4 mul4(float4 a, float4 b) {
    return make_float4(a.x * b.x, a.y * b.y, a.z * b.z, a.w * b.w);
}
static __device__ __forceinline__ short8 pack8(float4 a, float4 b) {
    return (short8){(short)f2bf(a.x), (short)f2bf(a.y), (short)f2bf(a.z), (short)f2bf(a.w),
                    (short)f2bf(b.x), (short)f2bf(b.y), (short)f2bf(b.z), (short)f2bf(b.w)};
}

// ---------------- K0a: weight transposes (fp32) + wfrag (bf16, frag order) ---
__global__ void k0a_prep(const float* __restrict__ lin2_w, const float* __restrict__ lin3_w,
                         const float* __restrict__ mlp_w1, const float* __restrict__ mlp_w2,
                         const float* __restrict__ linv1_w, const float* __restrict__ linv2_w,
                         const float* __restrict__ linv3_w,
                         float* __restrict__ wT2, float* __restrict__ wT3,
                         float* __restrict__ wTm1, float* __restrict__ wTm2,
                         unsigned short* __restrict__ wfrag) {
    int gid = blockIdx.x * 256 + threadIdx.x;
    int task = gid >> 14;
    int idx = gid & 16383;
    if (task < 4) {
        int e = idx & 127, dd = idx >> 7;
        const float* src = task == 0 ? lin2_w : task == 1 ? lin3_w : task == 2 ? mlp_w1 : mlp_w2;
        float* dst = task == 0 ? wT2 : task == 1 ? wT3 : task == 2 ? wTm1 : wTm2;
        dst[dd * 128 + e] = src[e * 128 + dd];
    } else {
        int mat = task - 4;
        const float* src = mat == 0 ? linv1_w : mat == 1 ? linv2_w : linv3_w;
        int e = idx >> 7, k = idx & 127;
        int dst = ((((e >> 4) * 12 + (mat * 4 + (k >> 5))) * 4 + ((k >> 3) & 3)) * 16 + (e & 15)) * 8
                  + (k & 7);
        wfrag[dst] = f2bf(src[idx] * (1.0f / 3.0f));
    }
}

// ---------------- K0b: s_v2t[b,d] = sum_m gv2[b,m,m,d] (coalesced rows) ------
__global__ void k0b_trace(const float* __restrict__ gv2, float* __restrict__ s_v2t) {
    int b = blockIdx.x, d = threadIdx.x;           // 8 x 128
    const float* p = gv2 + (size_t)b * (M_ * M_ * D_) + d;
    float acc = 0.f;
    #pragma unroll 8
    for (int m = 0; m < 128; ++m) acc += p[(size_t)m * 16512];
    s_v2t[b * 128 + d] = acc;
}

// ---------------- K0c: g1[b,e] = (lin1(s_v2t)+b1)*gs --------------------------
__global__ void k0c_g1(const float* __restrict__ s_v2t, const float* __restrict__ lin1_w,
                       const float* __restrict__ lin1_b, const float* __restrict__ gs,
                       float* __restrict__ g1) {
    __shared__ float sv[128];
    int b = blockIdx.x, e = threadIdx.x;
    sv[e] = s_v2t[b * 128 + e];
    __syncthreads();
    const float* w = lin1_w + e * 128;
    float acc = 0.f;
    #pragma unroll 4
    for (int dd = 0; dd < 128; ++dd) acc = fmaf(sv[dd], w[dd], acc);
    g1[b * 128 + e] = (acc + lin1_b[e]) * gs[b * 128 + e];
}

// ---------------- K1v3: T2 via bf16 MFMA, FULL-LINE coalesced staging ---------
// Block tile = 32n x 32c x 32d (one 128B line per row-chunk -> 100% line use).
// LDS: A[d][n][m'] / B[d][c][m'] bf16, row pad 36, m-group XOR (f&3) + row XOR
// (f>>2) swizzles to spread transpose writes. Wave w owns d-planes 4w..4w+3.
// mfma_f32_16x16x32_bf16 (proven), m-chunks of 32, 4 phases.
// Output: unchanged verified T2 fragment layout:
//   ushort idx = ((b*256+n)*2 + (c>>6))*16384 + ((c>>4)&3)*2048 + (d>>3)*128
//              + (c&15)*8 + (d&7)
__global__ __launch_bounds__(512, 1) void k1_T2(const float* __restrict__ v,
                                                const float* __restrict__ gv2,
                                                unsigned short* __restrict__ t2base) {
    __shared__ __attribute__((aligned(16))) unsigned short sm[73728]; // A@0, B@36864; ep overlays
    int bid = blockIdx.x;
    int b = bid & 7;                       // all same-b blocks on one XCD
    int r = bid >> 3;
    int ct = r & 3, dq = (r >> 2) & 3, nt = r >> 4;
    int n0 = nt * 32, c0 = ct * 32, d0 = dq * 32;
    int t = threadIdx.x;
    int w = t >> 6, lane = t & 63, ln15 = lane & 15, kgrp = lane >> 4;
    int f = t & 7;                         // float4 slot within the 128B line
    int g = t >> 3;                        // line-group id (0..63)
    int fsw = (f & 3) << 2;                // m-group swizzle bits
    int frw = f >> 2;                      // row swizzle bit

    f32x4 acc[4][2][2];
    #pragma unroll
    for (int p = 0; p < 4; ++p)
        #pragma unroll
        for (int i2 = 0; i2 < 2; ++i2)
            #pragma unroll
            for (int j2 = 0; j2 < 2; ++j2) acc[p][i2][j2] = (f32x4){0.f, 0.f, 0.f, 0.f};

    for (int mc = 0; mc < 4; ++mc) {
        int m0 = mc * 32;
        // stage A: v[b, n0+na, m0+ma, d0..+32), 1024 lines, 16 slots
        #pragma unroll
        for (int i = 0; i < 16; ++i) {
            int L = i * 64 + g;
            int na = L >> 5, ma = L & 31;
            float4 x = *(const float4*)(v + (((size_t)(b * N_ + n0 + na) * M_) + m0 + ma) * D_
                                          + d0 + f * 4);
            int mp = ma ^ fsw;
            int np = na ^ frw;
            #pragma unroll
            for (int j = 0; j < 4; ++j)
                sm[(f * 4 + j) * 1152 + np * 36 + mp] = bfhu(((const float*)&x)[j]);
        }
        // stage B: gv2[b, m0+ma, c0+ca, d0..+32)
        #pragma unroll
        for (int i = 0; i < 16; ++i) {
            int L = i * 64 + g;
            int ma = L >> 5, ca = L & 31;
            float4 x = *(const float4*)(gv2 + (((size_t)(b * M_ + m0 + ma) * M_) + c0 + ca) * D_
                                           + d0 + f * 4);
            int mp = ma ^ fsw;
            int cp = ca ^ frw;
            #pragma unroll
            for (int j = 0; j < 4; ++j)
                sm[36864 + (f * 4 + j) * 1152 + cp * 36 + mp] = bfhu(((const float*)&x)[j]);
        }
        __syncthreads();
        // compute: wave w -> d-planes 4w..4w+3
        #pragma unroll
        for (int p = 0; p < 4; ++p) {
            int d = w * 4 + p;
            int dbA = d * 1152, dbB = 36864 + d * 1152;
            int sw = w & 3, nsw = (w >> 2) & 1;
            int g0 = ((kgrp * 2) ^ sw) * 4, g1 = ((kgrp * 2 + 1) ^ sw) * 4;
            short8 aF[2], bF[2];
            #pragma unroll
            for (int u2 = 0; u2 < 2; ++u2) {
                int row = ((u2 * 16 + ln15) ^ nsw) * 36;
                short4v lo = *(const short4v*)&sm[dbA + row + g0];
                short4v hi = *(const short4v*)&sm[dbA + row + g1];
                aF[u2] = __builtin_shufflevector(lo, hi, 0, 1, 2, 3, 4, 5, 6, 7);
                short4v lo2 = *(const short4v*)&sm[dbB + row + g0];
                short4v hi2 = *(const short4v*)&sm[dbB + row + g1];
                bF[u2] = __builtin_shufflevector(lo2, hi2, 0, 1, 2, 3, 4, 5, 6, 7);
            }
            #pragma unroll
            for (int i2 = 0; i2 < 2; ++i2)
                #pragma unroll
                for (int j2 = 0; j2 < 2; ++j2)
                    acc[p][i2][j2] = __builtin_amdgcn_mfma_f32_16x16x32_bf16(
                        aF[i2], bF[j2], acc[p][i2][j2], 0, 0, 0);
        }
        __syncthreads();
    }
    // epilogue: acc -> ep[n][c][d-swz] (pad 40, oct-XOR), then 16B chunk stores
    #pragma unroll
    for (int p = 0; p < 4; ++p) {
        int d = w * 4 + p;
        #pragma unroll
        for (int i2 = 0; i2 < 2; ++i2)
            #pragma unroll
            for (int j2 = 0; j2 < 2; ++j2)
                #pragma unroll
                for (int q = 0; q < 4; ++q) {
                    int n = i2 * 16 + kgrp * 4 + q;
                    int c = j2 * 16 + ln15;
                    int X = ((n >> 2) & 3) ^ (c & 3);
                    sm[(n * 32 + c) * 40 + (d ^ (X << 3))] = bfhu(acc[p][i2][j2][q]);
                }
    }
    __syncthreads();
    #pragma unroll
    for (int i = 0; i < 8; ++i) {
        int u = i * 512 + t;
        int n = u >> 7, c = (u >> 2) & 31, oct = u & 3;
        int X = ((n >> 2) & 3) ^ (c & 3);
        short8 x = *(const short8*)&sm[(n * 32 + c) * 40 + ((oct ^ X) << 3)];
        int cg = c0 + c;
        int octg = dq * 4 + oct;
        size_t idx = ((size_t)((b * N_ + n0 + n) * 2 + (cg >> 6))) * 16384
                   + (size_t)((cg >> 4) & 3) * 2048 + (size_t)octg * 128 + (cg & 15) * 8;
        *(short8*)(t2base + idx) = x;
    }
}

// ---------------- K2v6: v_new GEMM, weights in LDS; fused s_vv ----------------
__global__ __launch_bounds__(512, 2) void k2_vnew(
        const float* __restrict__ s, const float* __restrict__ v,
        const float* __restrict__ gs, const float* __restrict__ gv,
        const unsigned short* __restrict__ wfrag,
        float* __restrict__ vnew, float* __restrict__ svv) {
    __shared__ unsigned short smw[49152];
    __shared__ float part[2][4][128];
    int t = threadIdx.x;
    int w = t >> 6;
    int sb = w >> 2;
    int w4 = w & 3;
    int kb2 = blockIdx.x * 2 + sb;
    int b = kb2 >> 8;
    int lane = t & 63, ln15 = lane & 15, kgrp = lane >> 4;

    #pragma unroll
    for (int r = 0; r < 12; ++r) {
        int idx = (r * 512 + t) * 8;
        *(short8*)&smw[idx] = *(const short8*)(wfrag + idx);
    }
    const unsigned short* t2u = (const unsigned short*)(vnew + (size_t)kb2 * 16384);
    short8 aT[2][4];
    #pragma unroll
    for (int h = 0; h < 2; ++h) {
        int rt = w4 * 2 + h;
        const unsigned short* tb = t2u + (rt >> 2) * 16384 + ((rt & 3) * 16 + kgrp) * 128 + ln15 * 8;
        #pragma unroll
        for (int kk = 0; kk < 4; ++kk)
            aT[h][kk] = *(const short8*)(tb + kk * 512);
    }
    const float* srow = s + (size_t)kb2 * 128;
    const float* gsr  = gs + (size_t)b * 128;
    float4 ss[8], qq[8];
    #pragma unroll
    for (int kk = 0; kk < 4; ++kk) {
        int dd = kk * 32 + kgrp * 8;
        ss[kk * 2]     = *(const float4*)(srow + dd);
        ss[kk * 2 + 1] = *(const float4*)(srow + dd + 4);
        qq[kk * 2]     = *(const float4*)(gsr + dd);
        qq[kk * 2 + 1] = *(const float4*)(gsr + dd + 4);
    }
    __syncthreads();

    float psum[8] = {0.f, 0.f, 0.f, 0.f, 0.f, 0.f, 0.f, 0.f};
    #pragma unroll
    for (int h = 0; h < 2; ++h) {
        int rt = w4 * 2 + h;
        int ca = rt * 16 + ln15;
        const float* gvr = gv + ((size_t)b * M_ + ca) * D_;
        const float* vr  = v + ((size_t)kb2 * M_ + ca) * D_;
        short8 aD[8];
        #pragma unroll
        for (int kk = 0; kk < 4; ++kk) {
            int dd = kk * 32 + kgrp * 8;
            float4 g0 = *(const float4*)(gvr + dd), g1 = *(const float4*)(gvr + dd + 4);
            float4 v0 = *(const float4*)(vr + dd),  v1 = *(const float4*)(vr + dd + 4);
            aD[kk]     = pack8(mul4(ss[kk * 2], g0), mul4(ss[kk * 2 + 1], g1));
            aD[4 + kk] = pack8(mul4(qq[kk * 2], v0), mul4(qq[kk * 2 + 1], v1));
        }
        float* outp = vnew + (size_t)kb2 * 16384 + (rt >> 2) * 8192;
        int rowl = (rt & 3) * 16 + kgrp * 4;
        const float* grow = gv + ((size_t)b * M_ + rt * 16 + kgrp * 4) * D_;
        #pragma unroll
        for (int ct = 0; ct < 8; ++ct) {
            f32x4 acc = {0.f, 0.f, 0.f, 0.f};
            #pragma unroll
            for (int kk = 0; kk < 12; ++kk) {
                short8 a = (kk < 4) ? aT[h][kk] : aD[kk - 4];
                short8 bfr = *(const short8*)&smw[(((ct * 12 + kk) * 4 + kgrp) * 16 + ln15) * 8];
                acc = __builtin_amdgcn_mfma_f32_16x16x32_bf16(a, bfr, acc, 0, 0, 0);
            }
            int e = ct * 16 + ln15;
            #pragma unroll
            for (int q = 0; q < 4; ++q) {
                outp[(size_t)(rowl + q) * 128 + e] = acc[q];
                psum[ct] = fmaf(grow[(size_t)q * 128 + e], acc[q], psum[ct]);
            }
        }
    }
    #pragma unroll
    for (int ct = 0; ct < 8; ++ct) {
        psum[ct] += __shfl_xor(psum[ct], 16);
        psum[ct] += __shfl_xor(psum[ct], 32);
    }
    if (kgrp == 0) {
        #pragma unroll
        for (int ct = 0; ct < 8; ++ct) part[sb][w4][ct * 16 + ln15] = psum[ct];
    }
    __syncthreads();
    int tl = t & 255;
    int sb2 = t >> 8;
    if (tl < 128) {
        int kbo = blockIdx.x * 2 + sb2;
        svv[(size_t)kbo * 128 + tl] =
            part[sb2][0][tl] + part[sb2][1][tl] + part[sb2][2][tl] + part[sb2][3][tl];
    }
}

// ---------------- K4: s-path linears + products + MLP -------------------------
__global__ __launch_bounds__(256) void k4_spath(
        const float* __restrict__ s, const float* __restrict__ svv,
        const float* __restrict__ g1,
        const float* __restrict__ wT2, const float* __restrict__ lin2_b,
        const float* __restrict__ wT3, const float* __restrict__ lin3_b,
        const float* __restrict__ wTm1, const float* __restrict__ mlp_b1,
        const float* __restrict__ wTm2, const float* __restrict__ mlp_b2,
        float* __restrict__ sout) {
    __shared__ float xs[8][128], xv[8][128], pre[8][128], hbuf[8][128];
    int t = threadIdx.x;
    int rowb = blockIdx.x * 8;
    int b = rowb >> 8;
    #pragma unroll
    for (int i = 0; i < 4; ++i) {
        int vi = i * 256 + t;
        int r = vi >> 7, dd = vi & 127;
        xs[r][dd] = s[(size_t)(rowb + r) * 128 + dd];
        xv[r][dd] = svv[(size_t)(rowb + r) * 128 + dd];
    }
    __syncthreads();
    int e = t & 127, h2 = t >> 7;
    float b2 = lin2_b[e], b3 = lin3_b[e], g1v = g1[b * 128 + e];
    float a2[4] = {b2, b2, b2, b2}, a3[4] = {b3, b3, b3, b3};
    for (int dd = 0; dd < 128; ++dd) {
        float w2 = wT2[dd * 128 + e], w3 = wT3[dd * 128 + e];
        #pragma unroll
        for (int r = 0; r < 4; ++r) {
            a2[r] = fmaf(xs[h2 * 4 + r][dd], w2, a2[r]);
            a3[r] = fmaf(xv[h2 * 4 + r][dd], w3, a3[r]);
        }
    }
    #pragma unroll
    for (int r = 0; r < 4; ++r) pre[h2 * 4 + r][e] = g1v * a2[r] * a3[r];
    __syncthreads();
    float bm1 = mlp_b1[e];
    float ah[4] = {bm1, bm1, bm1, bm1};
    for (int dd = 0; dd < 128; ++dd) {
        float w = wTm1[dd * 128 + e];
        #pragma unroll
        for (int r = 0; r < 4; ++r) ah[r] = fmaf(pre[h2 * 4 + r][dd], w, ah[r]);
    }
    #pragma unroll
    for (int r = 0; r < 4; ++r) hbuf[h2 * 4 + r][e] = fmaxf(ah[r], 0.f);
    __syncthreads();
    float bm2 = mlp_b2[e];
    float ao[4] = {bm2, bm2, bm2, bm2};
    for (int dd = 0; dd < 128; ++dd) {
        float w = wTm2[dd * 128 + e];
        #pragma unroll
        for (int r = 0; r < 4; ++r) ao[r] = fmaf(hbuf[h2 * 4 + r][dd], w, ao[r]);
    }
    #pragma unroll
    for (int r = 0; r < 4; ++r) sout[(size_t)(rowb + h2 * 4 + r) * 128 + e] = ao[r];
}

extern "C" void kernel_launch(void* const* d_in, const int* in_sizes, int n_in,
                              void* d_out, int out_size, void* d_ws, size_t ws_size,
                              hipStream_t stream) {
    const float* s       = (const float*)d_in[0];
    const float* v       = (const float*)d_in[1];
    const float* gs      = (const float*)d_in[2];
    const float* gv      = (const float*)d_in[3];
    const float* gv2     = (const float*)d_in[4];
    const float* lin1_w  = (const float*)d_in[5];
    const float* lin1_b  = (const float*)d_in[6];
    const float* lin2_w  = (const float*)d_in[7];
    const float* lin2_b  = (const float*)d_in[8];
    const float* lin3_w  = (const float*)d_in[9];
    const float* lin3_b  = (const float*)d_in[10];
    const float* linv1_w = (const float*)d_in[11];
    const float* linv2_w = (const float*)d_in[12];
    const float* linv3_w = (const float*)d_in[13];
    const float* mlp_w1  = (const float*)d_in[14];
    const float* mlp_b1  = (const float*)d_in[15];
    const float* mlp_w2  = (const float*)d_in[16];
    const float* mlp_b2  = (const float*)d_in[17];

    float* sout = (float*)d_out;
    float* vnew = (float*)d_out + 262144;   // v_new region; doubles as T2 (bf16,
                                            // fragment layout) between K1 and K2

    float* wsf   = (float*)d_ws;
    float* wT2   = wsf;
    float* wT3   = wsf + 16384;
    float* wTm1  = wsf + 32768;
    float* wTm2  = wsf + 49152;
    float* s_v2t = wsf + 65536;
    float* g1    = wsf + 66560;
    float* svv   = wsf + 67584;
    unsigned short* wfrag = (unsigned short*)(wsf + 329728);   // 96 KB

    k0a_prep<<<448, 256, 0, stream>>>(lin2_w, lin3_w, mlp_w1, mlp_w2,
                                      linv1_w, linv2_w, linv3_w,
                                      wT2, wT3, wTm1, wTm2, wfrag);
    k0b_trace<<<8, 128, 0, stream>>>(gv2, s_v2t);
    k0c_g1<<<8, 128, 0, stream>>>(s_v2t, lin1_w, lin1_b, gs, g1);
    k1_T2<<<1024, 512, 0, stream>>>(v, gv2, (unsigned short*)vnew);
    k2_vnew<<<1024, 512, 0, stream>>>(s, v, gs, gv, wfrag, vnew, svv);
    k4_spath<<<256, 256, 0, stream>>>(s, svv, g1, wT2, lin2_b, wT3, lin3_b,
                                      wTm1, mlp_b1, wTm2, mlp_b2, sout);
}

// Round 8
// 263.175 us; speedup vs baseline: 1.4988x; 1.4988x over previous
//
#include <hip/hip_runtime.h>
#include <hip/hip_bf16.h>
#include <stdint.h>

#define B_ 8
#define N_ 256
#define M_ 128
#define D_ 128

typedef __attribute__((ext_vector_type(8))) short short8;
typedef __attribute__((ext_vector_type(4))) short short4v;
typedef __attribute__((ext_vector_type(4))) float f32x4;

static __device__ __forceinline__ unsigned short f2bf(float x) {
    union { float f; unsigned int u; } c; c.f = x;
    unsigned int r = (c.u + 0x7FFFu + ((c.u >> 16) & 1u)) >> 16;
    return (unsigned short)r;
}
static __device__ __forceinline__ unsigned short bfhu(float x) {
    union { float f; unsigned int u; } c; c.f = x;
    return (unsigned short)((c.u + 0x8000u) >> 16);
}
static __device__ __forceinline__ unsigned int pkhu(float a, float b) {
    union { float f; unsigned int u; } ca, cb; ca.f = a; cb.f = b;
    return ((ca.u + 0x8000u) >> 16) | ((cb.u + 0x8000u) & 0xFFFF0000u);
}
static __device__ __forceinline__ float4 mul4(float4 a, float4 b) {
    return make_float4(a.x * b.x, a.y * b.y, a.z * b.z, a.w * b.w);
}
static __device__ __forceinline__ short8 pack8(float4 a, float4 b) {
    return (short8){(short)f2bf(a.x), (short)f2bf(a.y), (short)f2bf(a.z), (short)f2bf(a.w),
                    (short)f2bf(b.x), (short)f2bf(b.y), (short)f2bf(b.z), (short)f2bf(b.w)};
}

// ---------------- K0a: weight transposes (fp32) + wfrag (bf16, frag order) ---
__global__ void k0a_prep(const float* __restrict__ lin2_w, const float* __restrict__ lin3_w,
                         const float* __restrict__ mlp_w1, const float* __restrict__ mlp_w2,
                         const float* __restrict__ linv1_w, const float* __restrict__ linv2_w,
                         const float* __restrict__ linv3_w,
                         float* __restrict__ wT2, float* __restrict__ wT3,
                         float* __restrict__ wTm1, float* __restrict__ wTm2,
                         unsigned short* __restrict__ wfrag) {
    int gid = blockIdx.x * 256 + threadIdx.x;
    int task = gid >> 14;
    int idx = gid & 16383;
    if (task < 4) {
        int e = idx & 127, dd = idx >> 7;
        const float* src = task == 0 ? lin2_w : task == 1 ? lin3_w : task == 2 ? mlp_w1 : mlp_w2;
        float* dst = task == 0 ? wT2 : task == 1 ? wT3 : task == 2 ? wTm1 : wTm2;
        dst[dd * 128 + e] = src[e * 128 + dd];
    } else {
        int mat = task - 4;
        const float* src = mat == 0 ? linv1_w : mat == 1 ? linv2_w : linv3_w;
        int e = idx >> 7, k = idx & 127;
        int dst = ((((e >> 4) * 12 + (mat * 4 + (k >> 5))) * 4 + ((k >> 3) & 3)) * 16 + (e & 15)) * 8
                  + (k & 7);
        wfrag[dst] = f2bf(src[idx] * (1.0f / 3.0f));
    }
}

// ---------------- K0b: s_v2t[b,d] = sum_m gv2[b,m,m,d] ------------------------
__global__ void k0b_trace(const float* __restrict__ gv2, float* __restrict__ s_v2t) {
    int b = blockIdx.x, d = threadIdx.x;
    const float* p = gv2 + (size_t)b * (M_ * M_ * D_) + d;
    float acc = 0.f;
    #pragma unroll 8
    for (int m = 0; m < 128; ++m) acc += p[(size_t)m * 16512];
    s_v2t[b * 128 + d] = acc;
}

// ---------------- K0c: g1[b,e] = (lin1(s_v2t)+b1)*gs --------------------------
__global__ void k0c_g1(const float* __restrict__ s_v2t, const float* __restrict__ lin1_w,
                       const float* __restrict__ lin1_b, const float* __restrict__ gs,
                       float* __restrict__ g1) {
    __shared__ float sv[128];
    int b = blockIdx.x, e = threadIdx.x;
    sv[e] = s_v2t[b * 128 + e];
    __syncthreads();
    const float* w = lin1_w + e * 128;
    float acc = 0.f;
    #pragma unroll 4
    for (int dd = 0; dd < 128; ++dd) acc = fmaf(sv[dd], w[dd], acc);
    g1[b * 128 + e] = (acc + lin1_b[e]) * gs[b * 128 + e];
}

// ---------------- KT_v: vT[b,d,n*M+m] = bf16(v[b,n,m,d]) ----------------------
// Per block: 128 nm-rows x 128 d, LDS 128x136 transpose, both sides coalesced.
__global__ __launch_bounds__(256) void kt_v(const float* __restrict__ v,
                                            unsigned short* __restrict__ vT) {
    __shared__ unsigned short tl[128 * 136];
    int bid = blockIdx.x;
    int b = bid >> 8;
    int R0 = (bid & 255) * 128;
    int t = threadIdx.x;
    const float* src = v + ((size_t)b * 32768 + R0) * 128;
    #pragma unroll
    for (int i = 0; i < 16; ++i) {
        int flat = i * 256 + t;
        int row = flat >> 5, slot = flat & 31;
        float4 x = *(const float4*)(src + (size_t)row * 128 + slot * 4);
        #pragma unroll
        for (int j = 0; j < 4; ++j) {
            int d = slot * 4 + j;
            tl[d * 136 + (row ^ (((d >> 2) & 7) << 3))] = bfhu(((const float*)&x)[j]);
        }
    }
    __syncthreads();
    #pragma unroll
    for (int i = 0; i < 8; ++i) {
        int flat = i * 256 + t;
        int d = flat >> 4, rs = flat & 15;
        short8 y = *(const short8*)&tl[d * 136 + ((rs * 8) ^ (((d >> 2) & 7) << 3))];
        *(short8*)(vT + (size_t)(b * 128 + d) * 32768 + R0 + rs * 8) = y;
    }
}

// ---------------- KT_g: gT[b,d,c,m] = bf16(gv2[b,m,c,d]) ----------------------
__global__ __launch_bounds__(256) void kt_g(const float* __restrict__ gv2,
                                            unsigned short* __restrict__ gT) {
    __shared__ unsigned short tl[128 * 136];
    int bid = blockIdx.x;
    int b = bid >> 7;
    int c = bid & 127;
    int t = threadIdx.x;
    const float* src = gv2 + ((size_t)(b * 128) * 128 + c) * 128;
    #pragma unroll
    for (int i = 0; i < 16; ++i) {
        int flat = i * 256 + t;
        int m = flat >> 5, slot = flat & 31;
        float4 x = *(const float4*)(src + (size_t)m * 16384 + slot * 4);
        #pragma unroll
        for (int j = 0; j < 4; ++j) {
            int d = slot * 4 + j;
            tl[d * 136 + (m ^ (((d >> 2) & 7) << 3))] = bfhu(((const float*)&x)[j]);
        }
    }
    __syncthreads();
    #pragma unroll
    for (int i = 0; i < 8; ++i) {
        int flat = i * 256 + t;
        int d = flat >> 4, ms = flat & 15;
        short8 y = *(const short8*)&tl[d * 136 + ((ms * 8) ^ (((d >> 2) & 7) << 3))];
        *(short8*)(gT + ((size_t)(b * 128 + d) * 128 + c) * 128 + ms * 8) = y;
    }
}

// ---------------- K1fast: T2 GEMM from pre-transposed bf16 inputs -------------
// Tiling/fragments/epilogue/T2 layout verbatim from verified R5 kernel; staging
// is now a linear bf16 copy (short8 -> ds_write_b128), fully coalesced.
__global__ __launch_bounds__(512, 2) void k1_T2_fast(const unsigned short* __restrict__ vT,
                                                     const unsigned short* __restrict__ gT,
                                                     unsigned short* __restrict__ t2base) {
    __shared__ unsigned short sm[40960];   // A:[8][64][40]@0  B:@20480; epilogue overlays
    int bid = blockIdx.x;
    int b = bid & 7;
    int r = bid >> 3;
    int nt = r & 3, ch = (r >> 2) & 1, dc = r >> 3;
    int n0 = nt * 64, c0 = ch * 64, d0 = dc * 8;
    int t = threadIdx.x;
    int w = t >> 6, lane = t & 63, ln15 = lane & 15, kg = lane >> 4;

    f32x4 acc[4][4];
    #pragma unroll
    for (int i = 0; i < 4; ++i)
        #pragma unroll
        for (int j = 0; j < 4; ++j) acc[i][j] = (f32x4){0.f, 0.f, 0.f, 0.f};

    for (int mc = 0; mc < 4; ++mc) {
        int m0 = mc * 32;
        #pragma unroll
        for (int i = 0; i < 4; ++i) {
            int flat = i * 512 + t;            // [0,2048): d(8) x x(64) x ms(4)
            int d = flat >> 8, x = (flat >> 2) & 63, ms = flat & 3;
            short8 a = *(const short8*)(vT + ((size_t)(b * 128 + d0 + d) * 256 + n0 + x) * 128
                                           + m0 + ms * 8);
            *(short8*)&sm[d * 2560 + x * 40 + ms * 8] = a;
            short8 g = *(const short8*)(gT + ((size_t)(b * 128 + d0 + d) * 128 + c0 + x) * 128
                                           + m0 + ms * 8);
            *(short8*)&sm[20480 + d * 2560 + x * 40 + ms * 8] = g;
        }
        __syncthreads();
        short8 af[4], bf[4];
        #pragma unroll
        for (int i = 0; i < 4; ++i)
            af[i] = *(const short8*)&sm[w * 2560 + (i * 16 + ln15) * 40 + kg * 8];
        #pragma unroll
        for (int j = 0; j < 4; ++j)
            bf[j] = *(const short8*)&sm[20480 + w * 2560 + (j * 16 + ln15) * 40 + kg * 8];
        #pragma unroll
        for (int i = 0; i < 4; ++i)
            #pragma unroll
            for (int j = 0; j < 4; ++j)
                acc[i][j] = __builtin_amdgcn_mfma_f32_16x16x32_bf16(af[i], bf[j], acc[i][j], 0, 0, 0);
        __syncthreads();
    }
    // epilogue (R6-verified): ep[n][c][w] pad 520, then coalesced chunk store
    #pragma unroll
    for (int i = 0; i < 4; ++i)
        #pragma unroll
        for (int j = 0; j < 4; ++j)
            #pragma unroll
            for (int q = 0; q < 4; ++q) {
                int n = i * 16 + kg * 4 + q;
                int c = j * 16 + ln15;
                sm[n * 520 + c * 8 + w] = bfhu(acc[i][j][q]);
            }
    __syncthreads();
    #pragma unroll
    for (int p = 0; p < 8; ++p) {
        int u = p * 512 + t;
        int n = u >> 6;
        int c = u & 63;
        short8 x = *(const short8*)&sm[n * 520 + c * 8];
        size_t kb = (size_t)(b * N_ + n0 + n) * 2 + ch;
        *(short8*)(t2base + kb * 16384 + (size_t)((c >> 4) * 16 + dc) * 128 + (c & 15) * 8) = x;
    }
}

// ---------------- K1 legacy (R5-measured fallback, f32 fused staging) ---------
__global__ __launch_bounds__(512, 4) void k1_T2_legacy(const float* __restrict__ v,
                                                       const float* __restrict__ gv2,
                                                       unsigned short* __restrict__ t2base) {
    __shared__ unsigned short sm[40960];
    int bid = blockIdx.x;
    int b = bid & 7;
    int r = bid >> 3;
    int nt = r & 3, ch = (r >> 2) & 1, dc = r >> 3;
    int n0 = nt * 64, c0 = ch * 64, d0 = dc * 8;
    int t = threadIdx.x;
    int w = t >> 6, lane = t & 63, ln15 = lane & 15, kg = lane >> 4;

    f32x4 acc[4][4];
    #pragma unroll
    for (int i = 0; i < 4; ++i)
        #pragma unroll
        for (int j = 0; j < 4; ++j) acc[i][j] = (f32x4){0.f, 0.f, 0.f, 0.f};

    int d0l = (t & 1) * 4;
    int am = (t >> 1) & 31, anb = t >> 6;
    int bc = (t >> 1) & 63, bmb = t >> 7;

    for (int mc = 0; mc < 4; ++mc) {
        int m0 = mc * 32;
        {
            const float* src = v + (((size_t)(b * N_ + n0) * M_ + m0 + am) * D_ + d0 + d0l);
            #pragma unroll
            for (int p = 0; p < 8; ++p) {
                int n = p * 8 + anb;
                float4 x = *(const float4*)(src + (size_t)n * (M_ * D_));
                #pragma unroll
                for (int j = 0; j < 4; ++j)
                    sm[(d0l + j) * 2560 + n * 40 + am] = f2bf(((const float*)&x)[j]);
            }
        }
        {
            const float* src = gv2 + (((size_t)(b * M_ + m0) * M_ + c0 + bc) * D_ + d0 + d0l);
            #pragma unroll
            for (int p = 0; p < 8; ++p) {
                int m = p * 4 + bmb;
                float4 x = *(const float4*)(src + (size_t)m * (M_ * D_));
                #pragma unroll
                for (int j = 0; j < 4; ++j)
                    sm[20480 + (d0l + j) * 2560 + bc * 40 + m] = f2bf(((const float*)&x)[j]);
            }
        }
        __syncthreads();
        short8 af[4], bf[4];
        #pragma unroll
        for (int i = 0; i < 4; ++i)
            af[i] = *(const short8*)&sm[w * 2560 + (i * 16 + ln15) * 40 + kg * 8];
        #pragma unroll
        for (int j = 0; j < 4; ++j)
            bf[j] = *(const short8*)&sm[20480 + w * 2560 + (j * 16 + ln15) * 40 + kg * 8];
        #pragma unroll
        for (int i = 0; i < 4; ++i)
            #pragma unroll
            for (int j = 0; j < 4; ++j)
                acc[i][j] = __builtin_amdgcn_mfma_f32_16x16x32_bf16(af[i], bf[j], acc[i][j], 0, 0, 0);
        __syncthreads();
    }
    #pragma unroll
    for (int i = 0; i < 4; ++i)
        #pragma unroll
        for (int j = 0; j < 4; ++j)
            #pragma unroll
            for (int q = 0; q < 4; ++q) {
                int n = i * 16 + kg * 4 + q;
                int c = j * 16 + ln15;
                sm[(n * 64 + c) * 8 + w] = f2bf(acc[i][j][q]);
            }
    __syncthreads();
    #pragma unroll
    for (int p = 0; p < 8; ++p) {
        int u = p * 512 + t;
        int n = u >> 6;
        int c = u & 63;
        short8 x = *(const short8*)&sm[(n * 64 + c) * 8];
        size_t kb = (size_t)(b * N_ + n0 + n) * 2 + ch;
        *(short8*)(t2base + kb * 16384 + (size_t)((c >> 4) * 16 + dc) * 128 + (c & 15) * 8) = x;
    }
}

// ---------------- K2v6: v_new GEMM, weights in LDS; fused s_vv ----------------
__global__ __launch_bounds__(512, 2) void k2_vnew(
        const float* __restrict__ s, const float* __restrict__ v,
        const float* __restrict__ gs, const float* __restrict__ gv,
        const unsigned short* __restrict__ wfrag,
        float* __restrict__ vnew, float* __restrict__ svv) {
    __shared__ unsigned short smw[49152];
    __shared__ float part[2][4][128];
    int t = threadIdx.x;
    int w = t >> 6;
    int sb = w >> 2;
    int w4 = w & 3;
    int kb2 = blockIdx.x * 2 + sb;
    int b = kb2 >> 8;
    int lane = t & 63, ln15 = lane & 15, kgrp = lane >> 4;

    #pragma unroll
    for (int r = 0; r < 12; ++r) {
        int idx = (r * 512 + t) * 8;
        *(short8*)&smw[idx] = *(const short8*)(wfrag + idx);
    }
    const unsigned short* t2u = (const unsigned short*)(vnew + (size_t)kb2 * 16384);
    short8 aT[2][4];
    #pragma unroll
    for (int h = 0; h < 2; ++h) {
        int rt = w4 * 2 + h;
        const unsigned short* tb = t2u + (rt >> 2) * 16384 + ((rt & 3) * 16 + kgrp) * 128 + ln15 * 8;
        #pragma unroll
        for (int kk = 0; kk < 4; ++kk)
            aT[h][kk] = *(const short8*)(tb + kk * 512);
    }
    const float* srow = s + (size_t)kb2 * 128;
    const float* gsr  = gs + (size_t)b * 128;
    float4 ss[8], qq[8];
    #pragma unroll
    for (int kk = 0; kk < 4; ++kk) {
        int dd = kk * 32 + kgrp * 8;
        ss[kk * 2]     = *(const float4*)(srow + dd);
        ss[kk * 2 + 1] = *(const float4*)(srow + dd + 4);
        qq[kk * 2]     = *(const float4*)(gsr + dd);
        qq[kk * 2 + 1] = *(const float4*)(gsr + dd + 4);
    }
    __syncthreads();

    float psum[8] = {0.f, 0.f, 0.f, 0.f, 0.f, 0.f, 0.f, 0.f};
    #pragma unroll
    for (int h = 0; h < 2; ++h) {
        int rt = w4 * 2 + h;
        int ca = rt * 16 + ln15;
        const float* gvr = gv + ((size_t)b * M_ + ca) * D_;
        const float* vr  = v + ((size_t)kb2 * M_ + ca) * D_;
        short8 aD[8];
        #pragma unroll
        for (int kk = 0; kk < 4; ++kk) {
            int dd = kk * 32 + kgrp * 8;
            float4 g0 = *(const float4*)(gvr + dd), g1 = *(const float4*)(gvr + dd + 4);
            float4 v0 = *(const float4*)(vr + dd),  v1 = *(const float4*)(vr + dd + 4);
            aD[kk]     = pack8(mul4(ss[kk * 2], g0), mul4(ss[kk * 2 + 1], g1));
            aD[4 + kk] = pack8(mul4(qq[kk * 2], v0), mul4(qq[kk * 2 + 1], v1));
        }
        float* outp = vnew + (size_t)kb2 * 16384 + (rt >> 2) * 8192;
        int rowl = (rt & 3) * 16 + kgrp * 4;
        const float* grow = gv + ((size_t)b * M_ + rt * 16 + kgrp * 4) * D_;
        #pragma unroll
        for (int ct = 0; ct < 8; ++ct) {
            f32x4 acc = {0.f, 0.f, 0.f, 0.f};
            #pragma unroll
            for (int kk = 0; kk < 12; ++kk) {
                short8 a = (kk < 4) ? aT[h][kk] : aD[kk - 4];
                short8 bfr = *(const short8*)&smw[(((ct * 12 + kk) * 4 + kgrp) * 16 + ln15) * 8];
                acc = __builtin_amdgcn_mfma_f32_16x16x32_bf16(a, bfr, acc, 0, 0, 0);
            }
            int e = ct * 16 + ln15;
            #pragma unroll
            for (int q = 0; q < 4; ++q) {
                outp[(size_t)(rowl + q) * 128 + e] = acc[q];
                psum[ct] = fmaf(grow[(size_t)q * 128 + e], acc[q], psum[ct]);
            }
        }
    }
    #pragma unroll
    for (int ct = 0; ct < 8; ++ct) {
        psum[ct] += __shfl_xor(psum[ct], 16);
        psum[ct] += __shfl_xor(psum[ct], 32);
    }
    if (kgrp == 0) {
        #pragma unroll
        for (int ct = 0; ct < 8; ++ct) part[sb][w4][ct * 16 + ln15] = psum[ct];
    }
    __syncthreads();
    int tl = t & 255;
    int sb2 = t >> 8;
    if (tl < 128) {
        int kbo = blockIdx.x * 2 + sb2;
        svv[(size_t)kbo * 128 + tl] =
            part[sb2][0][tl] + part[sb2][1][tl] + part[sb2][2][tl] + part[sb2][3][tl];
    }
}

// ---------------- K4: s-path linears + products + MLP -------------------------
__global__ __launch_bounds__(256) void k4_spath(
        const float* __restrict__ s, const float* __restrict__ svv,
        const float* __restrict__ g1,
        const float* __restrict__ wT2, const float* __restrict__ lin2_b,
        const float* __restrict__ wT3, const float* __restrict__ lin3_b,
        const float* __restrict__ wTm1, const float* __restrict__ mlp_b1,
        const float* __restrict__ wTm2, const float* __restrict__ mlp_b2,
        float* __restrict__ sout) {
    __shared__ float xs[8][128], xv[8][128], pre[8][128], hbuf[8][128];
    int t = threadIdx.x;
    int rowb = blockIdx.x * 8;
    int b = rowb >> 8;
    #pragma unroll
    for (int i = 0; i < 4; ++i) {
        int vi = i * 256 + t;
        int r = vi >> 7, dd = vi & 127;
        xs[r][dd] = s[(size_t)(rowb + r) * 128 + dd];
        xv[r][dd] = svv[(size_t)(rowb + r) * 128 + dd];
    }
    __syncthreads();
    int e = t & 127, h2 = t >> 7;
    float b2 = lin2_b[e], b3 = lin3_b[e], g1v = g1[b * 128 + e];
    float a2[4] = {b2, b2, b2, b2}, a3[4] = {b3, b3, b3, b3};
    for (int dd = 0; dd < 128; ++dd) {
        float w2 = wT2[dd * 128 + e], w3 = wT3[dd * 128 + e];
        #pragma unroll
        for (int r = 0; r < 4; ++r) {
            a2[r] = fmaf(xs[h2 * 4 + r][dd], w2, a2[r]);
            a3[r] = fmaf(xv[h2 * 4 + r][dd], w3, a3[r]);
        }
    }
    #pragma unroll
    for (int r = 0; r < 4; ++r) pre[h2 * 4 + r][e] = g1v * a2[r] * a3[r];
    __syncthreads();
    float bm1 = mlp_b1[e];
    float ah[4] = {bm1, bm1, bm1, bm1};
    for (int dd = 0; dd < 128; ++dd) {
        float w = wTm1[dd * 128 + e];
        #pragma unroll
        for (int r = 0; r < 4; ++r) ah[r] = fmaf(pre[h2 * 4 + r][dd], w, ah[r]);
    }
    #pragma unroll
    for (int r = 0; r < 4; ++r) hbuf[h2 * 4 + r][e] = fmaxf(ah[r], 0.f);
    __syncthreads();
    float bm2 = mlp_b2[e];
    float ao[4] = {bm2, bm2, bm2, bm2};
    for (int dd = 0; dd < 128; ++dd) {
        float w = wTm2[dd * 128 + e];
        #pragma unroll
        for (int r = 0; r < 4; ++r) ao[r] = fmaf(hbuf[h2 * 4 + r][dd], w, ao[r]);
    }
    #pragma unroll
    for (int r = 0; r < 4; ++r) sout[(size_t)(rowb + h2 * 4 + r) * 128 + e] = ao[r];
}

extern "C" void kernel_launch(void* const* d_in, const int* in_sizes, int n_in,
                              void* d_out, int out_size, void* d_ws, size_t ws_size,
                              hipStream_t stream) {
    const float* s       = (const float*)d_in[0];
    const float* v       = (const float*)d_in[1];
    const float* gs      = (const float*)d_in[2];
    const float* gv      = (const float*)d_in[3];
    const float* gv2     = (const float*)d_in[4];
    const float* lin1_w  = (const float*)d_in[5];
    const float* lin1_b  = (const float*)d_in[6];
    const float* lin2_w  = (const float*)d_in[7];
    const float* lin2_b  = (const float*)d_in[8];
    const float* lin3_w  = (const float*)d_in[9];
    const float* lin3_b  = (const float*)d_in[10];
    const float* linv1_w = (const float*)d_in[11];
    const float* linv2_w = (const float*)d_in[12];
    const float* linv3_w = (const float*)d_in[13];
    const float* mlp_w1  = (const float*)d_in[14];
    const float* mlp_b1  = (const float*)d_in[15];
    const float* mlp_w2  = (const float*)d_in[16];
    const float* mlp_b2  = (const float*)d_in[17];

    float* sout = (float*)d_out;
    float* vnew = (float*)d_out + 262144;   // v_new region; doubles as T2 (bf16)

    float* wsf   = (float*)d_ws;
    float* wT2   = wsf;
    float* wT3   = wsf + 16384;
    float* wTm1  = wsf + 32768;
    float* wTm2  = wsf + 49152;
    float* s_v2t = wsf + 65536;
    float* g1    = wsf + 66560;
    float* svv   = wsf + 67584;
    unsigned short* wfrag = (unsigned short*)(wsf + 329728);   // 96 KB
    unsigned short* vT = (unsigned short*)((char*)d_ws + 2097152);     // 67.1 MB
    unsigned short* gT = (unsigned short*)((char*)d_ws + 69206016);    // 33.5 MB
    bool big = ws_size >= 102760448ULL;

    k0a_prep<<<448, 256, 0, stream>>>(lin2_w, lin3_w, mlp_w1, mlp_w2,
                                      linv1_w, linv2_w, linv3_w,
                                      wT2, wT3, wTm1, wTm2, wfrag);
    k0b_trace<<<8, 128, 0, stream>>>(gv2, s_v2t);
    k0c_g1<<<8, 128, 0, stream>>>(s_v2t, lin1_w, lin1_b, gs, g1);
    if (big) {
        kt_v<<<2048, 256, 0, stream>>>(v, vT);
        kt_g<<<1024, 256, 0, stream>>>(gv2, gT);
        k1_T2_fast<<<1024, 512, 0, stream>>>(vT, gT, (unsigned short*)vnew);
    } else {
        k1_T2_legacy<<<1024, 512, 0, stream>>>(v, gv2, (unsigned short*)vnew);
    }
    k2_vnew<<<1024, 512, 0, stream>>>(s, v, gs, gv, wfrag, vnew, svv);
    k4_spath<<<256, 256, 0, stream>>>(s, svv, g1, wT2, lin2_b, wT3, lin3_b,
                                      wTm1, mlp_b1, wTm2, mlp_b2, sout);
}